// Round 1
// baseline (860.806 us; speedup 1.0000x reference)
//
#include <hip/hip_runtime.h>
#include <cstdint>
#include <cstddef>

// Problem constants
#define B_SZ      2
#define S_LEN     2048
#define HID_DIM   1024
#define N_HEAD    16
#define D_HEAD    64
#define INNER_DIM 1024

typedef __attribute__((ext_vector_type(8))) short bf16x8;   // 8 x bf16 (4 VGPRs)
typedef __attribute__((ext_vector_type(4))) float f32x4;    // MFMA 16x16 C/D

// round-to-nearest-even fp32 -> bf16 (avoids hip_bf16 API variance)
__device__ __forceinline__ unsigned short f2bf(float f) {
  unsigned int u = __float_as_uint(f);
  u += 0x7fffu + ((u >> 16) & 1u);
  return (unsigned short)(u >> 16);
}

// async global->LDS, 16B per lane; dest = wave-uniform base + lane*16
__device__ __forceinline__ void gload_lds16(const void* g, void* l) {
  __builtin_amdgcn_global_load_lds((const __attribute__((address_space(1))) void*)g,
                                   (__attribute__((address_space(3))) void*)l,
                                   16, 0, 0);
}

// ---------------------------------------------------------------- cast fp32->bf16
__global__ void cast_bf16_kernel(const float* __restrict__ in,
                                 unsigned short* __restrict__ out, int n4) {
  int i = blockIdx.x * blockDim.x + threadIdx.x;
  if (i < n4) {
    float4 v = ((const float4*)in)[i];
    ushort4 o;
    o.x = f2bf(v.x); o.y = f2bf(v.y); o.z = f2bf(v.z); o.w = f2bf(v.w);
    ((ushort4*)out)[i] = o;
  }
}

// ------------------------------------------- transpose + cast: W[K][N] -> Wt[N][K] bf16
__global__ void transpose_cast_kernel(const float* __restrict__ in,
                                      unsigned short* __restrict__ out,
                                      int rows, int cols) {
  __shared__ float tile[32][33];
  int bx = blockIdx.x * 32;          // col base in `in`
  int by = blockIdx.y * 32;          // row base in `in`
  int tx = threadIdx.x & 31;
  int ty = threadIdx.x >> 5;         // 0..7
#pragma unroll
  for (int i = 0; i < 32; i += 8)
    tile[ty + i][tx] = in[(size_t)(by + ty + i) * cols + bx + tx];
  __syncthreads();
#pragma unroll
  for (int i = 0; i < 32; i += 8)
    out[(size_t)(bx + ty + i) * rows + by + tx] = f2bf(tile[tx][ty + i]);
}

// ---------------------------------------------------------------- GEMM  C = A @ Bt^T + bias
// A: [M][1024] bf16 row-major.  Bt: [N][1024] bf16 row-major (pre-transposed B).
// Tile 128(M) x 64(N) x 64(K). 256 thr = 4 waves (2x2), wave does 64x32.
// LDS tiles XOR-swizzled: 16B segment seg stored at seg ^ (row & 7)  (NSEG=8 -> 2-way free).
// MODE 0: bf16 out row-major [M][1024]
// MODE 1: bf16 out transposed to [B][H][D][S]  (for V)
// MODE 2: fp32 out row-major [M][1024]
template <int MODE>
__global__ __launch_bounds__(256, 2)
void gemm_bt_kernel(const unsigned short* __restrict__ A,
                    const unsigned short* __restrict__ Bt,
                    const float* __restrict__ bias,
                    void* __restrict__ out) {
  constexpr int K = 1024;
  __shared__ unsigned short Asm[128 * 64];
  __shared__ unsigned short Bsm[64 * 64];

  const int tid = threadIdx.x;
  const int lane = tid & 63;
  const int w = tid >> 6;        // wave 0..3
  const int wm = w & 1;          // m half
  const int wn = w >> 1;         // n half
  const int c = lane & 15;
  const int g = lane >> 4;
  const int m0 = blockIdx.x * 128;
  const int n0 = blockIdx.y * 64;

  f32x4 acc[4][2];
  f32x4 zero = {0.f, 0.f, 0.f, 0.f};
#pragma unroll
  for (int mt = 0; mt < 4; ++mt)
#pragma unroll
    for (int nt = 0; nt < 2; ++nt) acc[mt][nt] = zero;

  for (int kk = 0; kk < K / 64; ++kk) {
    __syncthreads();                       // previous tile reads done
    const int k0 = kk * 64;
#pragma unroll
    for (int it = 0; it < 4; ++it) {       // A: 128x64x2B = 1024 slots
      int slot = it * 256 + tid;
      int r = slot >> 3, sp = slot & 7, seg = sp ^ (r & 7);
      gload_lds16(A + (size_t)(m0 + r) * K + k0 + seg * 8,
                  (char*)Asm + (it * 256 + w * 64) * 16);
    }
#pragma unroll
    for (int it = 0; it < 2; ++it) {       // B: 64x64x2B = 512 slots
      int slot = it * 256 + tid;
      int r = slot >> 3, sp = slot & 7, seg = sp ^ (r & 7);
      gload_lds16(Bt + (size_t)(n0 + r) * K + k0 + seg * 8,
                  (char*)Bsm + (it * 256 + w * 64) * 16);
    }
    __syncthreads();                       // staged (drains vmcnt)

#pragma unroll
    for (int ks = 0; ks < 2; ++ks) {
      bf16x8 aF[4];
#pragma unroll
      for (int mt = 0; mt < 4; ++mt) {
        int r = wm * 64 + mt * 16 + c;
        int seg = (ks * 4 + g) ^ (r & 7);
        aF[mt] = *(const bf16x8*)((const char*)Asm + r * 128 + seg * 16);
      }
#pragma unroll
      for (int nt = 0; nt < 2; ++nt) {
        int r = wn * 32 + nt * 16 + c;
        int seg = (ks * 4 + g) ^ (r & 7);
        bf16x8 bF = *(const bf16x8*)((const char*)Bsm + r * 128 + seg * 16);
#pragma unroll
        for (int mt = 0; mt < 4; ++mt)
          acc[mt][nt] = __builtin_amdgcn_mfma_f32_16x16x32_bf16(aF[mt], bF, acc[mt][nt], 0, 0, 0);
      }
    }
  }

  // epilogue: C row = m0 + wm*64 + mt*16 + g*4 + reg ; col = n0 + wn*32 + nt*16 + c
#pragma unroll
  for (int nt = 0; nt < 2; ++nt) {
    int n_g = n0 + wn * 32 + nt * 16 + c;
    float bv = bias[n_g];
#pragma unroll
    for (int mt = 0; mt < 4; ++mt) {
      int m_base = m0 + wm * 64 + mt * 16 + g * 4;
      if (MODE == 0) {
        unsigned short* o = (unsigned short*)out;
#pragma unroll
        for (int r = 0; r < 4; ++r)
          o[(size_t)(m_base + r) * INNER_DIM + n_g] = f2bf(acc[mt][nt][r] + bv);
      } else if (MODE == 1) {
        int b = m_base >> 11;            // /S_LEN
        int s = m_base & 2047;
        int h = n_g >> 6;
        int d = n_g & 63;
        ushort4 pk;
        pk.x = f2bf(acc[mt][nt][0] + bv);
        pk.y = f2bf(acc[mt][nt][1] + bv);
        pk.z = f2bf(acc[mt][nt][2] + bv);
        pk.w = f2bf(acc[mt][nt][3] + bv);
        *(ushort4*)((unsigned short*)out +
                    ((size_t)((b * N_HEAD + h) * D_HEAD + d)) * S_LEN + s) = pk;
      } else {
        float* o = (float*)out;
#pragma unroll
        for (int r = 0; r < 4; ++r)
          o[(size_t)(m_base + r) * HID_DIM + n_g] = acc[mt][nt][r] + bv;
      }
    }
  }
}

// ---------------------------------------------------------------- flash attention
// block = (q-tile of 128, head, batch); 4 waves x 32 q-rows.
// Qp,Kp: [B*S][1024] bf16.  Vp: [B][H][D][S] bf16 (pre-transposed).  Osm: [B*S][1024] bf16.
__global__ __launch_bounds__(256, 2)
void attn_kernel(const unsigned short* __restrict__ Qp,
                 const unsigned short* __restrict__ Kp,
                 const unsigned short* __restrict__ Vp,
                 const float* __restrict__ bias,   // [1][H][S][S]
                 const float* __restrict__ mask,   // [B][1][S][S]
                 unsigned short* __restrict__ Osm) {
  __shared__ unsigned short Ksm[128 * 64];    // [kv][d]   NSEG=8 swizzle
  __shared__ unsigned short Vsm[64 * 128];    // [d][kv]   NSEG=16 swizzle
  __shared__ unsigned short Psm[128 * 128];   // [q][kv]   NSEG=16 swizzle

  const int tid = threadIdx.x;
  const int lane = tid & 63;
  const int w = tid >> 6;
  const int c = lane & 15;
  const int g = lane >> 4;
  const int q0 = blockIdx.x * 128;
  const int h = blockIdx.y;
  const int b = blockIdx.z;

  // Q fragments direct from global (A-layout: m=c, k=g*8+j, 16B aligned)
  bf16x8 qF[2][2];
#pragma unroll
  for (int mt = 0; mt < 2; ++mt)
#pragma unroll
    for (int ks = 0; ks < 2; ++ks) {
      size_t row = (size_t)(b * S_LEN + q0 + w * 32 + mt * 16 + c);
      qF[mt][ks] = *(const bf16x8*)(Qp + row * INNER_DIM + h * D_HEAD + ks * 32 + g * 8);
    }

  float m_run[2][4], l_run[2][4];
  f32x4 oacc[2][4];
  f32x4 zero = {0.f, 0.f, 0.f, 0.f};
#pragma unroll
  for (int mt = 0; mt < 2; ++mt) {
#pragma unroll
    for (int r = 0; r < 4; ++r) { m_run[mt][r] = -1e30f; l_run[mt][r] = 0.f; }
#pragma unroll
    for (int dt = 0; dt < 4; ++dt) oacc[mt][dt] = zero;
  }

  const float c1 = 0.125f * 1.44269504088896340736f;  // /sqrt(64) * log2(e)
  const float c2 = 1.44269504088896340736f;

  for (int j = 0; j < S_LEN / 128; ++j) {
    __syncthreads();                 // previous iter LDS reads done
#pragma unroll
    for (int it = 0; it < 4; ++it) { // K tile: 128x64 -> 1024 slots
      int slot = it * 256 + tid;
      int r = slot >> 3, sp = slot & 7, seg = sp ^ (r & 7);
      gload_lds16(Kp + (size_t)(b * S_LEN + j * 128 + r) * INNER_DIM + h * D_HEAD + seg * 8,
                  (char*)Ksm + (it * 256 + w * 64) * 16);
    }
#pragma unroll
    for (int it = 0; it < 4; ++it) { // Vt tile: 64x128 -> 1024 slots
      int slot = it * 256 + tid;
      int r = slot >> 4, sp = slot & 15, seg = sp ^ (r & 15);
      gload_lds16(Vp + ((size_t)((b * N_HEAD + h) * D_HEAD + r)) * S_LEN + j * 128 + seg * 8,
                  (char*)Vsm + (it * 256 + w * 64) * 16);
    }
    __syncthreads();

    // S = Q K^T   (rows mt*16+g*4+reg, cols nt*16+c)
    f32x4 sAcc[2][8];
#pragma unroll
    for (int mt = 0; mt < 2; ++mt)
#pragma unroll
      for (int nt = 0; nt < 8; ++nt) sAcc[mt][nt] = zero;
#pragma unroll
    for (int ks = 0; ks < 2; ++ks)
#pragma unroll
      for (int nt = 0; nt < 8; ++nt) {
        int r = nt * 16 + c;
        int seg = (ks * 4 + g) ^ (r & 7);
        bf16x8 kF = *(const bf16x8*)((const char*)Ksm + r * 128 + seg * 16);
#pragma unroll
        for (int mt = 0; mt < 2; ++mt)
          sAcc[mt][nt] = __builtin_amdgcn_mfma_f32_16x16x32_bf16(qF[mt][ks], kF, sAcc[mt][nt], 0, 0, 0);
      }

    // t = ((s + bias) * 0.125 + mask) * log2e
#pragma unroll
    for (int mt = 0; mt < 2; ++mt)
#pragma unroll
      for (int nt = 0; nt < 8; ++nt)
#pragma unroll
        for (int r = 0; r < 4; ++r) {
          int qg = q0 + w * 32 + mt * 16 + g * 4 + r;
          int kv = j * 128 + nt * 16 + c;
          float bvf = bias[((size_t)h * S_LEN + qg) * S_LEN + kv];
          float mvf = mask[((size_t)b * S_LEN + qg) * S_LEN + kv];
          sAcc[mt][nt][r] = (sAcc[mt][nt][r] + bvf) * c1 + mvf * c2;
        }

    // online softmax (exp2 space); row stats shared by the 16 lanes of each quad
#pragma unroll
    for (int mt = 0; mt < 2; ++mt)
#pragma unroll
      for (int r = 0; r < 4; ++r) {
        float mx = sAcc[mt][0][r];
#pragma unroll
        for (int nt = 1; nt < 8; ++nt) mx = fmaxf(mx, sAcc[mt][nt][r]);
        mx = fmaxf(mx, __shfl_xor(mx, 1));
        mx = fmaxf(mx, __shfl_xor(mx, 2));
        mx = fmaxf(mx, __shfl_xor(mx, 4));
        mx = fmaxf(mx, __shfl_xor(mx, 8));
        float mnew = fmaxf(m_run[mt][r], mx);
        float alpha = exp2f(m_run[mt][r] - mnew);
        m_run[mt][r] = mnew;
        float ssum = 0.f;
#pragma unroll
        for (int nt = 0; nt < 8; ++nt) {
          float pv = exp2f(sAcc[mt][nt][r] - mnew);
          sAcc[mt][nt][r] = pv;
          ssum += pv;
        }
        ssum += __shfl_xor(ssum, 1);
        ssum += __shfl_xor(ssum, 2);
        ssum += __shfl_xor(ssum, 4);
        ssum += __shfl_xor(ssum, 8);
        l_run[mt][r] = l_run[mt][r] * alpha + ssum;
#pragma unroll
        for (int dt = 0; dt < 4; ++dt) oacc[mt][dt][r] *= alpha;
      }

    // P -> LDS (C-layout -> A-layout round trip; wave touches only its own 32 rows)
#pragma unroll
    for (int mt = 0; mt < 2; ++mt)
#pragma unroll
      for (int nt = 0; nt < 8; ++nt)
#pragma unroll
        for (int r = 0; r < 4; ++r) {
          int qr = w * 32 + mt * 16 + g * 4 + r;
          int kv = nt * 16 + c;
          int seg = (kv >> 3) ^ (qr & 15);
          *(unsigned short*)((char*)Psm + qr * 256 + seg * 16 + (kv & 7) * 2) =
              f2bf(sAcc[mt][nt][r]);
        }
    __syncthreads();

    // O += P @ V
#pragma unroll
    for (int ks = 0; ks < 4; ++ks) {
      bf16x8 aP[2];
#pragma unroll
      for (int mt = 0; mt < 2; ++mt) {
        int qr = w * 32 + mt * 16 + c;
        int seg = (ks * 4 + g) ^ (qr & 15);
        aP[mt] = *(const bf16x8*)((const char*)Psm + qr * 256 + seg * 16);
      }
#pragma unroll
      for (int dt = 0; dt < 4; ++dt) {
        int dr = dt * 16 + c;
        int seg = (ks * 4 + g) ^ (dr & 15);
        bf16x8 vF = *(const bf16x8*)((const char*)Vsm + dr * 256 + seg * 16);
#pragma unroll
        for (int mt = 0; mt < 2; ++mt)
          oacc[mt][dt] = __builtin_amdgcn_mfma_f32_16x16x32_bf16(aP[mt], vF, oacc[mt][dt], 0, 0, 0);
      }
    }
  }

  // normalize + store bf16 [B*S][INNER] (head-major cols)
#pragma unroll
  for (int mt = 0; mt < 2; ++mt)
#pragma unroll
    for (int r = 0; r < 4; ++r) {
      float inv = 1.f / l_run[mt][r];
      int qg = q0 + w * 32 + mt * 16 + g * 4 + r;
#pragma unroll
      for (int dt = 0; dt < 4; ++dt)
        Osm[(size_t)(b * S_LEN + qg) * INNER_DIM + h * D_HEAD + dt * 16 + c] =
            f2bf(oacc[mt][dt][r] * inv);
    }
}

// ---------------------------------------------------------------- launch
extern "C" void kernel_launch(void* const* d_in, const int* in_sizes, int n_in,
                              void* d_out, int out_size, void* d_ws, size_t ws_size,
                              hipStream_t stream) {
  const float* query = (const float*)d_in[0];
  const float* key   = (const float*)d_in[1];
  const float* value = (const float*)d_in[2];
  const float* mask  = (const float*)d_in[3];
  const float* bias  = (const float*)d_in[4];
  const float* Wq = (const float*)d_in[5];
  const float* bq = (const float*)d_in[6];
  const float* Wk = (const float*)d_in[7];
  const float* bk = (const float*)d_in[8];
  const float* Wv = (const float*)d_in[9];
  const float* bv = (const float*)d_in[10];
  const float* Wo = (const float*)d_in[11];
  const float* bo = (const float*)d_in[12];

  const size_t NTOK   = (size_t)B_SZ * S_LEN;       // 4096
  const size_t SZ_ACT = NTOK * INNER_DIM;           // 4 Mi elems
  const size_t SZ_W   = (size_t)HID_DIM * INNER_DIM;

  unsigned short* ws  = (unsigned short*)d_ws;      // 64 MiB total bf16
  unsigned short* qb  = ws;
  unsigned short* kb  = qb + SZ_ACT;
  unsigned short* vb  = kb + SZ_ACT;
  unsigned short* Wqt = vb + SZ_ACT;
  unsigned short* Wkt = Wqt + SZ_W;
  unsigned short* Wvt = Wkt + SZ_W;
  unsigned short* Wot = Wvt + SZ_W;
  unsigned short* Qp  = Wot + SZ_W;
  unsigned short* Kp  = Qp + SZ_ACT;
  unsigned short* Vp  = Kp + SZ_ACT;                // [B][H][D][S]
  unsigned short* Ob  = Vp + SZ_ACT;

  int n4 = (int)(SZ_ACT / 4);
  int cblk = (n4 + 255) / 256;
  cast_bf16_kernel<<<cblk, 256, 0, stream>>>(query, qb, n4);
  cast_bf16_kernel<<<cblk, 256, 0, stream>>>(key,   kb, n4);
  cast_bf16_kernel<<<cblk, 256, 0, stream>>>(value, vb, n4);

  dim3 tgrid(INNER_DIM / 32, HID_DIM / 32);
  transpose_cast_kernel<<<tgrid, 256, 0, stream>>>(Wq, Wqt, HID_DIM, INNER_DIM);
  transpose_cast_kernel<<<tgrid, 256, 0, stream>>>(Wk, Wkt, HID_DIM, INNER_DIM);
  transpose_cast_kernel<<<tgrid, 256, 0, stream>>>(Wv, Wvt, HID_DIM, INNER_DIM);
  transpose_cast_kernel<<<tgrid, 256, 0, stream>>>(Wo, Wot, INNER_DIM, HID_DIM);

  dim3 ggrid(NTOK / 128, INNER_DIM / 64);           // (32,16)
  gemm_bt_kernel<0><<<ggrid, 256, 0, stream>>>(qb, Wqt, bq, Qp);
  gemm_bt_kernel<0><<<ggrid, 256, 0, stream>>>(kb, Wkt, bk, Kp);
  gemm_bt_kernel<1><<<ggrid, 256, 0, stream>>>(vb, Wvt, bv, Vp);

  dim3 agrid(S_LEN / 128, N_HEAD, B_SZ);            // (16,16,2)
  attn_kernel<<<agrid, 256, 0, stream>>>(Qp, Kp, Vp, bias, mask, Ob);

  gemm_bt_kernel<2><<<ggrid, 256, 0, stream>>>(Ob, Wot, bo, d_out);
}

// Round 2
// 655.867 us; speedup vs baseline: 1.3125x; 1.3125x over previous
//
#include <hip/hip_runtime.h>
#include <cstdint>
#include <cstddef>

// Problem constants
#define B_SZ      2
#define S_LEN     2048
#define HID_DIM   1024
#define N_HEAD    16
#define D_HEAD    64
#define INNER_DIM 1024

// scale constants: scores = (s + bias)/8 + mask, softmax in exp2 space
// fold 0.125*log2(e) into Q at projection time; fused bias = bias*C1 + mask*C2
#define C1 0.18033688011112042f    /* 0.125 * log2(e) */
#define C2 1.44269504088896340736f /* log2(e) */

typedef __attribute__((ext_vector_type(8))) short bf16x8;   // 8 x bf16 (4 VGPRs)
typedef __attribute__((ext_vector_type(4))) float f32x4;    // MFMA 16x16 C/D

__device__ __forceinline__ unsigned short f2bf(float f) {
  unsigned int u = __float_as_uint(f);
  u += 0x7fffu + ((u >> 16) & 1u);
  return (unsigned short)(u >> 16);
}
__device__ __forceinline__ float bf2f(unsigned short u) {
  return __uint_as_float(((unsigned int)u) << 16);
}

// async global->LDS, 16B per lane; dest = wave-uniform base + lane*16
__device__ __forceinline__ void gload_lds16(const void* g, void* l) {
  __builtin_amdgcn_global_load_lds((const __attribute__((address_space(1))) void*)g,
                                   (__attribute__((address_space(3))) void*)l,
                                   16, 0, 0);
}

// ---------------------------------------------------------------- cast fp32->bf16 (x3)
__global__ void cast3_kernel(const float* __restrict__ i0, const float* __restrict__ i1,
                             const float* __restrict__ i2,
                             unsigned short* __restrict__ o0, unsigned short* __restrict__ o1,
                             unsigned short* __restrict__ o2, int n4) {
  int z = blockIdx.y;
  const float* in = (z == 0) ? i0 : (z == 1) ? i1 : i2;
  unsigned short* out = (z == 0) ? o0 : (z == 1) ? o1 : o2;
  int i = blockIdx.x * blockDim.x + threadIdx.x;
  if (i < n4) {
    float4 v = ((const float4*)in)[i];
    ushort4 o;
    o.x = f2bf(v.x); o.y = f2bf(v.y); o.z = f2bf(v.z); o.w = f2bf(v.w);
    ((ushort4*)out)[i] = o;
  }
}

// ------------------------------------------- transpose + cast: W[K][N] -> Wt[N][K] bf16
__global__ void transpose_cast_kernel(const float* __restrict__ in,
                                      unsigned short* __restrict__ out,
                                      int rows, int cols) {
  __shared__ float tile[32][33];
  int bx = blockIdx.x * 32;
  int by = blockIdx.y * 32;
  int tx = threadIdx.x & 31;
  int ty = threadIdx.x >> 5;
#pragma unroll
  for (int i = 0; i < 32; i += 8)
    tile[ty + i][tx] = in[(size_t)(by + ty + i) * cols + bx + tx];
  __syncthreads();
#pragma unroll
  for (int i = 0; i < 32; i += 8)
    out[(size_t)(bx + ty + i) * rows + by + tx] = f2bf(tile[tx][ty + i]);
}

// ---------------------------------------------------------------- GEMM core body macro
// A: [M][1024] bf16 row-major.  Bt: [N][1024] bf16 row-major.
// Tile 128(M) x 64(N) x 64(K); 256 thr = 4 waves (2x2), wave does 64x32.
// LDS XOR-swizzle: 16B segment stored at seg ^ (row & 7).

// Merged Q/K/V projection GEMM. z = blockIdx.z selects problem.
// z<2: bf16 row-major out (z==0 scaled by C1).  z==2: V, store transposed [B][H][D][S].
__global__ __launch_bounds__(256, 2)
void qkv_gemm_kernel(const unsigned short* __restrict__ Aq,
                     const unsigned short* __restrict__ Ak,
                     const unsigned short* __restrict__ Av,
                     const unsigned short* __restrict__ Wq,
                     const unsigned short* __restrict__ Wk,
                     const unsigned short* __restrict__ Wv,
                     const float* __restrict__ bq,
                     const float* __restrict__ bk,
                     const float* __restrict__ bv,
                     unsigned short* __restrict__ Oq,
                     unsigned short* __restrict__ Ok,
                     unsigned short* __restrict__ Ov) {
  constexpr int K = 1024;
  __shared__ unsigned short Asm[128 * 64];
  __shared__ unsigned short Bsm[64 * 64];

  const int z = blockIdx.z;
  const unsigned short* A  = (z == 0) ? Aq : (z == 1) ? Ak : Av;
  const unsigned short* Bt = (z == 0) ? Wq : (z == 1) ? Wk : Wv;
  const float* bias        = (z == 0) ? bq : (z == 1) ? bk : bv;
  const float scale        = (z == 0) ? C1 : 1.0f;

  const int tid = threadIdx.x;
  const int lane = tid & 63;
  const int w = tid >> 6;
  const int wm = w & 1;
  const int wn = w >> 1;
  const int c = lane & 15;
  const int g = lane >> 4;
  const int m0 = blockIdx.x * 128;
  const int n0 = blockIdx.y * 64;

  f32x4 acc[4][2];
  f32x4 zero = {0.f, 0.f, 0.f, 0.f};
#pragma unroll
  for (int mt = 0; mt < 4; ++mt)
#pragma unroll
    for (int nt = 0; nt < 2; ++nt) acc[mt][nt] = zero;

  for (int kk = 0; kk < K / 64; ++kk) {
    __syncthreads();
    const int k0 = kk * 64;
#pragma unroll
    for (int it = 0; it < 4; ++it) {
      int slot = it * 256 + tid;
      int r = slot >> 3, sp = slot & 7, seg = sp ^ (r & 7);
      gload_lds16(A + (size_t)(m0 + r) * K + k0 + seg * 8,
                  (char*)Asm + (it * 256 + w * 64) * 16);
    }
#pragma unroll
    for (int it = 0; it < 2; ++it) {
      int slot = it * 256 + tid;
      int r = slot >> 3, sp = slot & 7, seg = sp ^ (r & 7);
      gload_lds16(Bt + (size_t)(n0 + r) * K + k0 + seg * 8,
                  (char*)Bsm + (it * 256 + w * 64) * 16);
    }
    __syncthreads();

#pragma unroll
    for (int ks = 0; ks < 2; ++ks) {
      bf16x8 aF[4];
#pragma unroll
      for (int mt = 0; mt < 4; ++mt) {
        int r = wm * 64 + mt * 16 + c;
        int seg = (ks * 4 + g) ^ (r & 7);
        aF[mt] = *(const bf16x8*)((const char*)Asm + r * 128 + seg * 16);
      }
#pragma unroll
      for (int nt = 0; nt < 2; ++nt) {
        int r = wn * 32 + nt * 16 + c;
        int seg = (ks * 4 + g) ^ (r & 7);
        bf16x8 bF = *(const bf16x8*)((const char*)Bsm + r * 128 + seg * 16);
#pragma unroll
        for (int mt = 0; mt < 4; ++mt)
          acc[mt][nt] = __builtin_amdgcn_mfma_f32_16x16x32_bf16(aF[mt], bF, acc[mt][nt], 0, 0, 0);
      }
    }
  }

#pragma unroll
  for (int nt = 0; nt < 2; ++nt) {
    int n_g = n0 + wn * 32 + nt * 16 + c;
    float bvv = bias[n_g];
#pragma unroll
    for (int mt = 0; mt < 4; ++mt) {
      int m_base = m0 + wm * 64 + mt * 16 + g * 4;
      if (z == 2) {
        int b = m_base >> 11;
        int s = m_base & 2047;
        int hh = n_g >> 6;
        int d = n_g & 63;
        ushort4 pk;
        pk.x = f2bf(acc[mt][nt][0] + bvv);
        pk.y = f2bf(acc[mt][nt][1] + bvv);
        pk.z = f2bf(acc[mt][nt][2] + bvv);
        pk.w = f2bf(acc[mt][nt][3] + bvv);
        *(ushort4*)(Ov + ((size_t)((b * N_HEAD + hh) * D_HEAD + d)) * S_LEN + s) = pk;
      } else {
        unsigned short* o = (z == 0) ? Oq : Ok;
#pragma unroll
        for (int r = 0; r < 4; ++r)
          o[(size_t)(m_base + r) * INNER_DIM + n_g] = f2bf((acc[mt][nt][r] + bvv) * scale);
      }
    }
  }
}

// Out-projection GEMM: fp32 out.
__global__ __launch_bounds__(256, 2)
void out_gemm_kernel(const unsigned short* __restrict__ A,
                     const unsigned short* __restrict__ Bt,
                     const float* __restrict__ bias,
                     float* __restrict__ out) {
  constexpr int K = 1024;
  __shared__ unsigned short Asm[128 * 64];
  __shared__ unsigned short Bsm[64 * 64];

  const int tid = threadIdx.x;
  const int lane = tid & 63;
  const int w = tid >> 6;
  const int wm = w & 1;
  const int wn = w >> 1;
  const int c = lane & 15;
  const int g = lane >> 4;
  const int m0 = blockIdx.x * 128;
  const int n0 = blockIdx.y * 64;

  f32x4 acc[4][2];
  f32x4 zero = {0.f, 0.f, 0.f, 0.f};
#pragma unroll
  for (int mt = 0; mt < 4; ++mt)
#pragma unroll
    for (int nt = 0; nt < 2; ++nt) acc[mt][nt] = zero;

  for (int kk = 0; kk < K / 64; ++kk) {
    __syncthreads();
    const int k0 = kk * 64;
#pragma unroll
    for (int it = 0; it < 4; ++it) {
      int slot = it * 256 + tid;
      int r = slot >> 3, sp = slot & 7, seg = sp ^ (r & 7);
      gload_lds16(A + (size_t)(m0 + r) * K + k0 + seg * 8,
                  (char*)Asm + (it * 256 + w * 64) * 16);
    }
#pragma unroll
    for (int it = 0; it < 2; ++it) {
      int slot = it * 256 + tid;
      int r = slot >> 3, sp = slot & 7, seg = sp ^ (r & 7);
      gload_lds16(Bt + (size_t)(n0 + r) * K + k0 + seg * 8,
                  (char*)Bsm + (it * 256 + w * 64) * 16);
    }
    __syncthreads();

#pragma unroll
    for (int ks = 0; ks < 2; ++ks) {
      bf16x8 aF[4];
#pragma unroll
      for (int mt = 0; mt < 4; ++mt) {
        int r = wm * 64 + mt * 16 + c;
        int seg = (ks * 4 + g) ^ (r & 7);
        aF[mt] = *(const bf16x8*)((const char*)Asm + r * 128 + seg * 16);
      }
#pragma unroll
      for (int nt = 0; nt < 2; ++nt) {
        int r = wn * 32 + nt * 16 + c;
        int seg = (ks * 4 + g) ^ (r & 7);
        bf16x8 bF = *(const bf16x8*)((const char*)Bsm + r * 128 + seg * 16);
#pragma unroll
        for (int mt = 0; mt < 4; ++mt)
          acc[mt][nt] = __builtin_amdgcn_mfma_f32_16x16x32_bf16(aF[mt], bF, acc[mt][nt], 0, 0, 0);
      }
    }
  }

#pragma unroll
  for (int nt = 0; nt < 2; ++nt) {
    int n_g = n0 + wn * 32 + nt * 16 + c;
    float bvv = bias[n_g];
#pragma unroll
    for (int mt = 0; mt < 4; ++mt) {
      int m_base = m0 + wm * 64 + mt * 16 + g * 4;
#pragma unroll
      for (int r = 0; r < 4; ++r)
        out[(size_t)(m_base + r) * HID_DIM + n_g] = acc[mt][nt][r] + bvv;
    }
  }
}

// ---------------------------------------------------------------- flash attention
// block = 512 thr = 8 waves; q-tile 128, wave w owns q rows [w*16, w*16+16).
// Qp,Kp: [B*S][1024] bf16 (Q pre-scaled by C1).  Vp: [B][H][D][S] bf16.
// bias/mask fp32 fetched coalesced (float4), fused to bias*C1+mask*C2, bounced
// through the wave-private 4KB P-region as bf16, read back in C-layout.
__global__ __launch_bounds__(512, 4)
void attn_kernel(const unsigned short* __restrict__ Qp,
                 const unsigned short* __restrict__ Kp,
                 const unsigned short* __restrict__ Vp,
                 const float* __restrict__ bias,   // [1][H][S][S]
                 const float* __restrict__ mask,   // [B][1][S][S]
                 unsigned short* __restrict__ Osm) {
  __shared__ unsigned short Ksm[128 * 64];    // [kv][d]   NSEG8 swizzle   16 KB
  __shared__ unsigned short Vsm[64 * 128];    // [d][kv]   NSEG16 swizzle  16 KB
  __shared__ unsigned short Psm[128 * 128];   // [q][kv]   wave-private    32 KB

  const int tid = threadIdx.x;
  const int lane = tid & 63;
  const int w = tid >> 6;           // wave 0..7
  const int c = lane & 15;
  const int g = lane >> 4;
  const int q0 = blockIdx.x * 128;
  const int h = blockIdx.y;
  const int b = blockIdx.z;

  char* Pw = (char*)Psm + w * 4096;     // wave-private 16 rows x 256 B

  // Q fragments (A-layout: m=c, k=g*8+j), rows w*16+c
  bf16x8 qF[2];
  {
    size_t row = (size_t)(b * S_LEN + q0 + w * 16 + c);
#pragma unroll
    for (int ks = 0; ks < 2; ++ks)
      qF[ks] = *(const bf16x8*)(Qp + row * INNER_DIM + h * D_HEAD + ks * 32 + g * 8);
  }

  // coalesced bias/mask bases: lane covers (row lrow, cols lcol*4..lcol*4+3)
  const int lrow = lane >> 5;           // 0..1
  const int lcol = lane & 31;           // float4 index in 128-col row
  const float* bias_base = bias + ((size_t)h * S_LEN + q0 + w * 16 + lrow) * S_LEN + lcol * 4;
  const float* mask_base = mask + ((size_t)b * S_LEN + q0 + w * 16 + lrow) * S_LEN + lcol * 4;

  float m_run[4], l_run[4];
  f32x4 oacc[4];
  f32x4 zero = {0.f, 0.f, 0.f, 0.f};
#pragma unroll
  for (int r = 0; r < 4; ++r) { m_run[r] = -1e30f; l_run[r] = 0.f; }
#pragma unroll
  for (int dt = 0; dt < 4; ++dt) oacc[dt] = zero;

  for (int j = 0; j < S_LEN / 128; ++j) {
    __syncthreads();                 // all waves done reading Ksm/Vsm of prev iter
    // ---- stage K (128 kv x 64 d) and Vt (64 d x 128 kv), 512 thr x 2 slots each
#pragma unroll
    for (int it = 0; it < 2; ++it) {
      int slot = it * 512 + tid;
      int r = slot >> 3, sp = slot & 7, seg = sp ^ (r & 7);
      gload_lds16(Kp + (size_t)(b * S_LEN + j * 128 + r) * INNER_DIM + h * D_HEAD + seg * 8,
                  (char*)Ksm + (it * 512 + w * 64) * 16);
    }
#pragma unroll
    for (int it = 0; it < 2; ++it) {
      int slot = it * 512 + tid;
      int r = slot >> 4, sp = slot & 15, seg = sp ^ (r & 15);
      gload_lds16(Vp + ((size_t)((b * N_HEAD + h) * D_HEAD + r)) * S_LEN + j * 128 + seg * 8,
                  (char*)Vsm + (it * 512 + w * 64) * 16);
    }

    // ---- fused bias+mask: coalesced float4 loads -> bf16 -> wave-private LDS
    // overlaps the K/V DMA latency (all before the barrier). 2 chunks of 4 row-passes.
#pragma unroll
    for (int half = 0; half < 2; ++half) {
      float4 bl[4], ml[4];
#pragma unroll
      for (int p = 0; p < 4; ++p) {
        int pp = half * 4 + p;   // row pass: rows pp*2 + lrow
        bl[p] = *(const float4*)(bias_base + (size_t)(pp * 2) * S_LEN + j * 128);
        ml[p] = *(const float4*)(mask_base + (size_t)(pp * 2) * S_LEN + j * 128);
      }
#pragma unroll
      for (int p = 0; p < 4; ++p) {
        int pp = half * 4 + p;
        ushort4 fo;
        fo.x = f2bf(bl[p].x * C1 + ml[p].x * C2);
        fo.y = f2bf(bl[p].y * C1 + ml[p].y * C2);
        fo.z = f2bf(bl[p].z * C1 + ml[p].z * C2);
        fo.w = f2bf(bl[p].w * C1 + ml[p].w * C2);
        *(ushort4*)(Pw + (pp * 2 + lrow) * 256 + lcol * 8) = fo;
      }
    }
    __syncthreads();                 // K/V staged (drains vmcnt)

    // ---- S = Q K^T : q rows w*16+g*4+r, kv cols nt*16+c
    f32x4 sAcc[8];
#pragma unroll
    for (int nt = 0; nt < 8; ++nt) sAcc[nt] = zero;
#pragma unroll
    for (int ks = 0; ks < 2; ++ks)
#pragma unroll
      for (int nt = 0; nt < 8; ++nt) {
        int r = nt * 16 + c;
        int seg = (ks * 4 + g) ^ (r & 7);
        bf16x8 kF = *(const bf16x8*)((const char*)Ksm + r * 128 + seg * 16);
        sAcc[nt] = __builtin_amdgcn_mfma_f32_16x16x32_bf16(qF[ks], kF, sAcc[nt], 0, 0, 0);
      }

    // ---- t = s + fused   (s already in exp2-scaled space via Q prescale)
#pragma unroll
    for (int nt = 0; nt < 8; ++nt)
#pragma unroll
      for (int r = 0; r < 4; ++r) {
        int row_l = g * 4 + r;
        int kv_l = nt * 16 + c;
        sAcc[nt][r] += bf2f(*(const unsigned short*)(Pw + row_l * 256 + kv_l * 2));
      }

    // ---- online softmax (exp2 space); row shared by 16 lanes (same g)
#pragma unroll
    for (int r = 0; r < 4; ++r) {
      float mx = sAcc[0][r];
#pragma unroll
      for (int nt = 1; nt < 8; ++nt) mx = fmaxf(mx, sAcc[nt][r]);
      mx = fmaxf(mx, __shfl_xor(mx, 1));
      mx = fmaxf(mx, __shfl_xor(mx, 2));
      mx = fmaxf(mx, __shfl_xor(mx, 4));
      mx = fmaxf(mx, __shfl_xor(mx, 8));
      float mnew = fmaxf(m_run[r], mx);
      float alpha = __builtin_amdgcn_exp2f(m_run[r] - mnew);
      m_run[r] = mnew;
      float ssum = 0.f;
#pragma unroll
      for (int nt = 0; nt < 8; ++nt) {
        float pv = __builtin_amdgcn_exp2f(sAcc[nt][r] - mnew);
        sAcc[nt][r] = pv;
        ssum += pv;
      }
      ssum += __shfl_xor(ssum, 1);
      ssum += __shfl_xor(ssum, 2);
      ssum += __shfl_xor(ssum, 4);
      ssum += __shfl_xor(ssum, 8);
      l_run[r] = l_run[r] * alpha + ssum;
#pragma unroll
      for (int dt = 0; dt < 4; ++dt) oacc[dt][r] *= alpha;
    }

    // ---- P -> wave-private LDS (C-layout -> A-layout), NSEG16 swizzle on 16 rows
#pragma unroll
    for (int nt = 0; nt < 8; ++nt)
#pragma unroll
      for (int r = 0; r < 4; ++r) {
        int row_l = g * 4 + r;
        int kv = nt * 16 + c;
        int seg = (kv >> 3) ^ row_l;
        *(unsigned short*)(Pw + row_l * 256 + seg * 16 + (kv & 7) * 2) = f2bf(sAcc[nt][r]);
      }
    // wave-private region: no barrier needed (same-wave lgkmcnt ordering)

    // ---- O += P @ V
#pragma unroll
    for (int ks = 0; ks < 4; ++ks) {
      int segP = (ks * 4 + g) ^ c;               // row = c
      bf16x8 aP = *(const bf16x8*)(Pw + c * 256 + segP * 16);
#pragma unroll
      for (int dt = 0; dt < 4; ++dt) {
        int dr = dt * 16 + c;
        int segV = (ks * 4 + g) ^ (dr & 15);
        bf16x8 vF = *(const bf16x8*)((const char*)Vsm + dr * 256 + segV * 16);
        oacc[dt] = __builtin_amdgcn_mfma_f32_16x16x32_bf16(aP, vF, oacc[dt], 0, 0, 0);
      }
    }
  }

  // ---- normalize + store bf16 [B*S][INNER]
#pragma unroll
  for (int r = 0; r < 4; ++r) {
    float inv = 1.f / l_run[r];
    int qg = q0 + w * 16 + g * 4 + r;
#pragma unroll
    for (int dt = 0; dt < 4; ++dt)
      Osm[(size_t)(b * S_LEN + qg) * INNER_DIM + h * D_HEAD + dt * 16 + c] =
          f2bf(oacc[dt][r] * inv);
  }
}

// ---------------------------------------------------------------- launch
extern "C" void kernel_launch(void* const* d_in, const int* in_sizes, int n_in,
                              void* d_out, int out_size, void* d_ws, size_t ws_size,
                              hipStream_t stream) {
  const float* query = (const float*)d_in[0];
  const float* key   = (const float*)d_in[1];
  const float* value = (const float*)d_in[2];
  const float* mask  = (const float*)d_in[3];
  const float* bias  = (const float*)d_in[4];
  const float* Wq = (const float*)d_in[5];
  const float* bq = (const float*)d_in[6];
  const float* Wk = (const float*)d_in[7];
  const float* bk = (const float*)d_in[8];
  const float* Wv = (const float*)d_in[9];
  const float* bv = (const float*)d_in[10];
  const float* Wo = (const float*)d_in[11];
  const float* bo = (const float*)d_in[12];

  const size_t NTOK   = (size_t)B_SZ * S_LEN;       // 4096
  const size_t SZ_ACT = NTOK * INNER_DIM;           // 4 Mi elems
  const size_t SZ_W   = (size_t)HID_DIM * INNER_DIM;

  unsigned short* ws  = (unsigned short*)d_ws;
  unsigned short* qb  = ws;
  unsigned short* kb  = qb + SZ_ACT;
  unsigned short* vb  = kb + SZ_ACT;
  unsigned short* Wqt = vb + SZ_ACT;
  unsigned short* Wkt = Wqt + SZ_W;
  unsigned short* Wvt = Wkt + SZ_W;
  unsigned short* Wot = Wvt + SZ_W;
  unsigned short* Qp  = Wot + SZ_W;
  unsigned short* Kp  = Qp + SZ_ACT;
  unsigned short* Vp  = Kp + SZ_ACT;                // [B][H][D][S]
  unsigned short* Ob  = Vp + SZ_ACT;

  int n4 = (int)(SZ_ACT / 4);
  int cblk = (n4 + 255) / 256;
  dim3 cgrid(cblk, 3);
  cast3_kernel<<<cgrid, 256, 0, stream>>>(query, key, value, qb, kb, vb, n4);

  dim3 tgrid(INNER_DIM / 32, HID_DIM / 32);
  transpose_cast_kernel<<<tgrid, 256, 0, stream>>>(Wq, Wqt, HID_DIM, INNER_DIM);
  transpose_cast_kernel<<<tgrid, 256, 0, stream>>>(Wk, Wkt, HID_DIM, INNER_DIM);
  transpose_cast_kernel<<<tgrid, 256, 0, stream>>>(Wv, Wvt, HID_DIM, INNER_DIM);
  transpose_cast_kernel<<<tgrid, 256, 0, stream>>>(Wo, Wot, INNER_DIM, HID_DIM);

  dim3 ggrid(NTOK / 128, INNER_DIM / 64, 3);        // (32,16,3)
  qkv_gemm_kernel<<<ggrid, 256, 0, stream>>>(qb, kb, vb, Wqt, Wkt, Wvt,
                                             bq, bk, bv, Qp, Kp, Vp);

  dim3 agrid(S_LEN / 128, N_HEAD, B_SZ);            // (16,16,2)
  attn_kernel<<<agrid, 512, 0, stream>>>(Qp, Kp, Vp, bias, mask, Ob);

  dim3 ogrid(NTOK / 128, HID_DIM / 64);
  out_gemm_kernel<<<ogrid, 256, 0, stream>>>(Ob, Wot, bo, (float*)d_out);
}